// Round 1
// baseline (121.145 us; speedup 1.0000x reference)
//
#include <hip/hip_runtime.h>
#include <math.h>

constexpr int DEG = 64;
constexpr int KC  = 32;   // candidates
constexpr int D   = 64;
constexpr int STR = 72;   // padded LDS row stride (floats); rows 16B-aligned
constexpr float EPS = 1.1920929e-05f;  // 100 * eps_f32

// chunk-XOR swizzle: float index of 16B chunk `c` of row `r`
__device__ __forceinline__ int swz(int r, int c) {
    return r * STR + (((c) ^ (r >> 2)) << 2);
}

__global__ __launch_bounds__(64)
void rgc_kernel(const float* __restrict__ x,
                const int*   __restrict__ nbr,
                float*       __restrict__ out) {
    __shared__ float xn[DEG * STR];
    __shared__ float nrm[DEG];
    __shared__ float wsh[KC];

    const int n = blockIdx.x;
    const int l = threadIdx.x;   // 0..63, one wave

    const int my_idx = nbr[n * DEG + l];

    // ---- stage 64 rows into LDS (4 rows / iter, 16 lanes per row, float4) ----
    const int rsub = l >> 4;       // 0..3
    const int cw   = l & 15;       // chunk 0..15
    for (int t = 0; t < 16; ++t) {
        const int row = 4 * t + rsub;
        const int g   = __shfl(my_idx, row);
        const float4 v = *reinterpret_cast<const float4*>(x + ((size_t)g << 6) + (cw << 2));
        *reinterpret_cast<float4*>(&xn[swz(row, cw)]) = v;
    }
    __syncthreads();

    // ---- row norms: lane l owns row l ----
    {
        float s = 0.f;
        #pragma unroll
        for (int c = 0; c < 16; ++c) {
            const float4 v = *reinterpret_cast<const float4*>(&xn[swz(l, c)]);
            s += v.x * v.x + v.y * v.y + v.z * v.z + v.w * v.w;
        }
        nrm[l] = s;
    }
    __syncthreads();

    // ---- pairwise dots: lane tile = 4 k-rows x 8 m-rows ----
    const int kg = l >> 3;   // 0..7 -> k rows 4*kg..4*kg+3
    const int mg = l & 7;    // 0..7 -> m rows 8*mg..8*mg+7

    float acc[4][8];
    #pragma unroll
    for (int i = 0; i < 4; ++i)
        #pragma unroll
        for (int j = 0; j < 8; ++j) acc[i][j] = 0.f;

    #pragma unroll 2
    for (int c0 = 0; c0 < 16; ++c0) {
        float4 a[4], b[8];
        #pragma unroll
        for (int i = 0; i < 4; ++i)
            a[i] = *reinterpret_cast<const float4*>(&xn[swz(4 * kg + i, c0)]);
        #pragma unroll
        for (int j = 0; j < 8; ++j)
            b[j] = *reinterpret_cast<const float4*>(&xn[swz(8 * mg + j, c0)]);
        #pragma unroll
        for (int i = 0; i < 4; ++i)
            #pragma unroll
            for (int j = 0; j < 8; ++j)
                acc[i][j] += a[i].x * b[j].x + a[i].y * b[j].y
                           + a[i].z * b[j].z + a[i].w * b[j].w;
    }

    // ---- sq -> l2 -> partial dist over my 8 m's ----
    float pd[4];
    #pragma unroll
    for (int i = 0; i < 4; ++i) {
        const float nk = nrm[4 * kg + i];
        float s = 0.f;
        #pragma unroll
        for (int j = 0; j < 8; ++j) {
            const float sq = nk + nrm[8 * mg + j] - 2.0f * acc[i][j];
            s += sqrtf(fabsf(sq) + EPS);
        }
        pd[i] = s;
    }
    // reduce over the 8 m-groups (lane bits 0..2)
    #pragma unroll
    for (int sft = 1; sft <= 4; sft <<= 1) {
        #pragma unroll
        for (int i = 0; i < 4; ++i) pd[i] += __shfl_xor(pd[i], sft);
    }
    // pd[i] = dist[4*kg+i], replicated across each kg group

    // ---- softmax over 32 k's (s_k = -dist_k) ----
    float dmin = fminf(fminf(pd[0], pd[1]), fminf(pd[2], pd[3]));
    #pragma unroll
    for (int sft = 8; sft <= 32; sft <<= 1) dmin = fminf(dmin, __shfl_xor(dmin, sft));

    float e[4];
    float zs = 0.f;
    #pragma unroll
    for (int i = 0; i < 4; ++i) { e[i] = __expf(dmin - pd[i]); zs += e[i]; }
    #pragma unroll
    for (int sft = 8; sft <= 32; sft <<= 1) zs += __shfl_xor(zs, sft);

    if (mg == 0) {
        const float sc = 64.0f / zs;   // row_sum = DEG
        #pragma unroll
        for (int i = 0; i < 4; ++i) wsh[4 * kg + i] = e[i] * sc;
    }
    __syncthreads();

    // ---- output: out[n][l] = sum_k w[k] * xc[k][l] ----
    float o = 0.f;
    #pragma unroll
    for (int k = 0; k < KC; ++k)
        o += wsh[k] * xn[k * STR + ((((l >> 2) ^ (k >> 2)) << 2) | (l & 3))];
    out[(size_t)n * D + l] = o;
}

extern "C" void kernel_launch(void* const* d_in, const int* in_sizes, int n_in,
                              void* d_out, int out_size, void* d_ws, size_t ws_size,
                              hipStream_t stream) {
    const float* x   = (const float*)d_in[0];
    const int*   nbr = (const int*)d_in[1];
    float*       out = (float*)d_out;
    const int n_nodes = in_sizes[0] / D;   // 20000
    rgc_kernel<<<n_nodes, 64, 0, stream>>>(x, nbr, out);
}

// Round 2
// 84.098 us; speedup vs baseline: 1.4405x; 1.4405x over previous
//
#include <hip/hip_runtime.h>
#include <math.h>

typedef float f32x16 __attribute__((ext_vector_type(16)));
typedef __bf16 bf16x8 __attribute__((ext_vector_type(8)));
typedef unsigned short u16x8 __attribute__((ext_vector_type(8)));

constexpr int DEG = 64;
constexpr int KC  = 32;
constexpr int D   = 64;
constexpr float EPS = 1.1920929e-05f;  // 100 * f32 eps

// chunk-major bf16 LDS layout: 16B chunk c (8 bf16) of row r lives at
// ushort index c*512 + ((r^c)*8). Fragment reads (row varies over 32 lanes,
// chunk fixed per half) are lane-linear 512B segments -> conflict-free;
// the r^c XOR spreads staging writes (row varies only 4x per instr).
__device__ __forceinline__ int yidx(int row, int chunk) {
    return chunk * 512 + ((row ^ chunk) << 3);
}

__device__ __forceinline__ unsigned short bf16_rne(float f) {
    unsigned u = __float_as_uint(f);
    unsigned r = (u + 0x7FFFu + ((u >> 16) & 1u)) >> 16;
    return (unsigned short)r;
}

__global__ __launch_bounds__(128, 4)
void rgc_kernel(const float* __restrict__ x,
                const int*   __restrict__ nbr,
                float*       __restrict__ out) {
    __shared__ __align__(16) unsigned short yhi[4096];  // 8 KB
    __shared__ __align__(16) unsigned short ylo[4096];  // 8 KB
    __shared__ float nrm[64];
    __shared__ float wsh[KC];
    __shared__ float pdist[64];
    __shared__ float obuf[64];

    const int n = blockIdx.x;
    const int t = threadIdx.x;
    const int w = t >> 6;    // wave id = m-tile id
    const int l = t & 63;

    const int my_idx = nbr[n * DEG + l];

    // ---- stage 64 rows as bf16 hi/lo + norms: 4 iters x (16 rows x 8 chunks) ----
    const int srow = t >> 3;   // 0..15
    const int sc   = t & 7;    // chunk 0..7
    #pragma unroll
    for (int it = 0; it < 4; ++it) {
        const int row = it * 16 + srow;
        const int g   = __shfl(my_idx, row);
        const float* src = x + ((size_t)g << 6) + (sc << 3);
        const float4 v0 = *reinterpret_cast<const float4*>(src);
        const float4 v1 = *reinterpret_cast<const float4*>(src + 4);
        const float fv[8] = {v0.x, v0.y, v0.z, v0.w, v1.x, v1.y, v1.z, v1.w};
        float s = 0.f;
        u16x8 h, e;
        #pragma unroll
        for (int j = 0; j < 8; ++j) {
            const float f = fv[j];
            s += f * f;
            const unsigned short hb = bf16_rne(f);
            h[j] = hb;
            e[j] = bf16_rne(f - __uint_as_float((unsigned)hb << 16));
        }
        s += __shfl_xor(s, 1); s += __shfl_xor(s, 2); s += __shfl_xor(s, 4);
        if (sc == 0) nrm[row] = s;
        const int base = yidx(row, sc);
        *reinterpret_cast<u16x8*>(&yhi[base]) = h;
        *reinterpret_cast<u16x8*>(&ylo[base]) = e;
    }
    __syncthreads();

    // ---- fragments: A = rows 0..31 (k-rows); B = rows w*32.. (m-rows) ----
    // mfma_f32_32x32x16_bf16: A/B lane l -> row l&31, k = (l>>5)*8 + j
    const int arow = l & 31;
    const int kh   = l >> 5;
    bf16x8 ahi[4], alo[4], bhi[4], blo[4];
    #pragma unroll
    for (int s = 0; s < 4; ++s) {
        const int c  = 2 * s + kh;
        const int ab = yidx(arow, c);
        ahi[s] = *reinterpret_cast<bf16x8*>(&yhi[ab]);
        alo[s] = *reinterpret_cast<bf16x8*>(&ylo[ab]);
    }
    if (w == 0) {   // Gram symmetry: B-tile0 fragment == A fragment
        #pragma unroll
        for (int s = 0; s < 4; ++s) { bhi[s] = ahi[s]; blo[s] = alo[s]; }
    } else {
        #pragma unroll
        for (int s = 0; s < 4; ++s) {
            const int c  = 2 * s + kh;
            const int bb = yidx(32 + arow, c);
            bhi[s] = *reinterpret_cast<bf16x8*>(&yhi[bb]);
            blo[s] = *reinterpret_cast<bf16x8*>(&ylo[bb]);
        }
    }

    f32x16 acc = {};
    #pragma unroll
    for (int s = 0; s < 4; ++s)
        acc = __builtin_amdgcn_mfma_f32_32x32x16_bf16(ahi[s], bhi[s], acc, 0, 0, 0);
    #pragma unroll
    for (int s = 0; s < 4; ++s)
        acc = __builtin_amdgcn_mfma_f32_32x32x16_bf16(ahi[s], blo[s], acc, 0, 0, 0);
    #pragma unroll
    for (int s = 0; s < 4; ++s)
        acc = __builtin_amdgcn_mfma_f32_32x32x16_bf16(alo[s], bhi[s], acc, 0, 0, 0);

    // ---- sq -> l2 -> per-tile dist partials ----
    // C layout: m = w*32 + (l&31), k = (r&3) + 8*(r>>2) + 4*(l>>5)
    const float nm = nrm[w * 32 + (l & 31)];
    float pd[16];
    #pragma unroll
    for (int r = 0; r < 16; ++r) {
        const int k = (r & 3) + 8 * (r >> 2) + 4 * kh;
        const float sq = nrm[k] + nm - 2.0f * acc[r];
        pd[r] = sqrtf(fabsf(sq) + EPS);
    }
    #pragma unroll
    for (int m = 1; m <= 16; m <<= 1) {
        #pragma unroll
        for (int r = 0; r < 16; ++r) pd[r] += __shfl_xor(pd[r], m);
    }
    if ((l & 31) == 0) {
        #pragma unroll
        for (int r = 0; r < 16; ++r) {
            const int k = (r & 3) + 8 * (r >> 2) + 4 * kh;
            pdist[w * 32 + k] = pd[r];
        }
    }
    __syncthreads();

    // ---- softmax over 32 candidates (wave0 only) ----
    if (w == 0) {
        float dv[16];
        #pragma unroll
        for (int r = 0; r < 16; ++r) {
            const int k = (r & 3) + 8 * (r >> 2) + 4 * kh;
            dv[r] = pdist[k] + pdist[32 + k];
        }
        float dmin = dv[0];
        #pragma unroll
        for (int r = 1; r < 16; ++r) dmin = fminf(dmin, dv[r]);
        dmin = fminf(dmin, __shfl_xor(dmin, 32));
        float ev[16];
        float Z = 0.f;
        #pragma unroll
        for (int r = 0; r < 16; ++r) { ev[r] = __expf(dmin - dv[r]); Z += ev[r]; }
        Z += __shfl_xor(Z, 32);
        const float scw = 64.0f / Z;   // row_sum = DEG
        if ((l & 31) == 0) {
            #pragma unroll
            for (int r = 0; r < 16; ++r) {
                const int k = (r & 3) + 8 * (r >> 2) + 4 * kh;
                wsh[k] = ev[r] * scw;
            }
        }
    }
    __syncthreads();

    // ---- output: out[n][l] = sum_k w[k]*Y[k][l]; wave w does k in [16w,16w+16) ----
    const int oc = l >> 3;
    const int ow = l & 7;
    float o = 0.f;
    #pragma unroll
    for (int kk = 0; kk < 16; ++kk) {
        const int k  = w * 16 + kk;
        const int bi = yidx(k, oc) + ow;
        const float f = __uint_as_float((unsigned)yhi[bi] << 16)
                      + __uint_as_float((unsigned)ylo[bi] << 16);
        o += wsh[k] * f;
    }
    if (w == 1) obuf[l] = o;
    __syncthreads();
    if (w == 0) out[(size_t)n * D + l] = o + obuf[l];
}

extern "C" void kernel_launch(void* const* d_in, const int* in_sizes, int n_in,
                              void* d_out, int out_size, void* d_ws, size_t ws_size,
                              hipStream_t stream) {
    const float* x   = (const float*)d_in[0];
    const int*   nbr = (const int*)d_in[1];
    float*       out = (float*)d_out;
    const int n_nodes = in_sizes[0] / D;   // 20000
    rgc_kernel<<<n_nodes, 128, 0, stream>>>(x, nbr, out);
}

// Round 4
// 60.641 us; speedup vs baseline: 1.9977x; 1.3868x over previous
//
#include <hip/hip_runtime.h>
#include <math.h>

typedef float f32x16 __attribute__((ext_vector_type(16)));
typedef __bf16 bf16x8 __attribute__((ext_vector_type(8)));

constexpr int DEG = 64;
constexpr int KC  = 32;
constexpr int D   = 64;
constexpr float EPS = 1.1920929e-05f;  // 100 * f32 eps

// chunk-major bf16 LDS layout: 16B chunk c (8 bf16) of row r lives at
// ushort index c*512 + ((r^c)*8). Fragment reads (row varies over 32 lanes,
// chunk fixed per half) are lane-linear permuted 512B segments -> conflict-free.
__device__ __forceinline__ int yidx(int row, int chunk) {
    return chunk * 512 + ((row ^ chunk) << 3);
}

__global__ __launch_bounds__(128, 4)
void rgc_kernel(const float* __restrict__ x,
                const int*   __restrict__ nbr,
                float*       __restrict__ out) {
    __shared__ __align__(16) unsigned short yhi[4096];  // 8 KB
    __shared__ __align__(16) unsigned short ylo[4096];  // 8 KB
    __shared__ float nrm[64];
    __shared__ float wsh[KC];
    __shared__ float pdist[64];
    __shared__ float obuf[64];

    const int n = blockIdx.x;
    const int t = threadIdx.x;
    const int w = t >> 6;    // wave id = m-tile id
    const int l = t & 63;

    // ---- stage 64 rows as bf16 hi/lo + norms ----
    // thread handles row = it*16 + (t>>3), chunk = t&7 (8 floats)
    const int srow = t >> 3;
    const int sc   = t & 7;
    int gidx[4];
    #pragma unroll
    for (int it = 0; it < 4; ++it)
        gidx[it] = nbr[(n << 6) + it * 16 + srow];

    #pragma unroll
    for (int it = 0; it < 4; ++it) {
        const int row = it * 16 + srow;
        const float* src = x + ((size_t)gidx[it] << 6) + (sc << 3);
        const float4 v0 = *reinterpret_cast<const float4*>(src);
        const float4 v1 = *reinterpret_cast<const float4*>(src + 4);
        const float fv[8] = {v0.x, v0.y, v0.z, v0.w, v1.x, v1.y, v1.z, v1.w};
        float s = 0.f;
        bf16x8 h, e;
        #pragma unroll
        for (int j = 0; j < 8; ++j) {
            const float f = fv[j];
            s += f * f;
            const __bf16 hb = (__bf16)f;           // RNE via v_cvt
            h[j] = hb;
            e[j] = (__bf16)(f - (float)hb);
        }
        s += __shfl_xor(s, 1); s += __shfl_xor(s, 2); s += __shfl_xor(s, 4);
        if (sc == 0) nrm[row] = s;
        const int base = yidx(row, sc);
        *reinterpret_cast<bf16x8*>(&yhi[base]) = h;
        *reinterpret_cast<bf16x8*>(&ylo[base]) = e;
    }
    __syncthreads();

    // ---- fragments (operands SWAPPED vs naive): D = Xm · Xk^T ----
    // A-operand = m-rows (wave's tile), B-operand = k-rows 0..31.
    // => C: k = lane&31 (lane dim), m = (r&3)+8*(r>>2)+4*(lane>>5) (reg dim)
    const int frow = l & 31;
    const int kh   = l >> 5;
    bf16x8 amh[4], aml[4], bkh[4], bkl[4];
    #pragma unroll
    for (int s = 0; s < 4; ++s) {
        const int c  = 2 * s + kh;
        const int kb = yidx(frow, c);
        bkh[s] = *reinterpret_cast<bf16x8*>(&yhi[kb]);
        bkl[s] = *reinterpret_cast<bf16x8*>(&ylo[kb]);
    }
    if (w == 0) {   // Gram symmetry: m-rows 0..31 == k-rows 0..31
        #pragma unroll
        for (int s = 0; s < 4; ++s) { amh[s] = bkh[s]; aml[s] = bkl[s]; }
    } else {
        #pragma unroll
        for (int s = 0; s < 4; ++s) {
            const int c  = 2 * s + kh;
            const int mb = yidx(32 + frow, c);
            amh[s] = *reinterpret_cast<bf16x8*>(&yhi[mb]);
            aml[s] = *reinterpret_cast<bf16x8*>(&ylo[mb]);
        }
    }

    f32x16 acc = {};
    #pragma unroll
    for (int s = 0; s < 4; ++s)
        acc = __builtin_amdgcn_mfma_f32_32x32x16_bf16(amh[s], bkh[s], acc, 0, 0, 0);
    #pragma unroll
    for (int s = 0; s < 4; ++s)
        acc = __builtin_amdgcn_mfma_f32_32x32x16_bf16(amh[s], bkl[s], acc, 0, 0, 0);
    #pragma unroll
    for (int s = 0; s < 4; ++s)
        acc = __builtin_amdgcn_mfma_f32_32x32x16_bf16(aml[s], bkh[s], acc, 0, 0, 0);

    // ---- sq -> l2 -> dist partial: reduce over m IN REGISTERS ----
    const float nk = nrm[l & 31];
    const int   mb0 = w * 32 + 4 * kh;
    float4 nm4[4];
    #pragma unroll
    for (int q = 0; q < 4; ++q)
        nm4[q] = *reinterpret_cast<const float4*>(&nrm[mb0 + 8 * q]);  // broadcast

    float s = 0.f;
    #pragma unroll
    for (int r = 0; r < 16; ++r) {
        const float nm = ((const float*)&nm4[r >> 2])[r & 3];
        const float sq = nm + nk - 2.0f * acc[r];
        s += sqrtf(fabsf(sq) + EPS);
    }
    s += __shfl_xor(s, 32);       // combine the two m-halves
    if (l < 32) pdist[w * 32 + l] = s;
    __syncthreads();

    // ---- softmax over 32 candidates (both waves, redundant, lane-parallel) ----
    const int k = l & 31;
    const float d = pdist[k] + pdist[32 + k];
    float dmin = d;
    #pragma unroll
    for (int m = 1; m <= 16; m <<= 1) dmin = fminf(dmin, __shfl_xor(dmin, m));
    const float ez = __expf(dmin - d);
    float Z = ez;
    #pragma unroll
    for (int m = 1; m <= 16; m <<= 1) Z += __shfl_xor(Z, m);
    if (t < 32) wsh[k] = ez * (64.0f / Z);   // row_sum = DEG
    __syncthreads();

    // ---- output: out[n][l] = sum_k w[k]*Y[k][l]; wave w does k in [16w,16w+16) ----
    const int oc = l >> 3;
    const int ow = l & 7;
    float o = 0.f;
    #pragma unroll
    for (int kk = 0; kk < 16; ++kk) {
        const int kx = w * 16 + kk;
        const int bi = yidx(kx, oc) + ow;
        const float f = __uint_as_float((unsigned)yhi[bi] << 16)
                      + __uint_as_float((unsigned)ylo[bi] << 16);
        o += wsh[kx] * f;
    }
    if (w == 1) obuf[l] = o;
    __syncthreads();
    if (w == 0) out[(size_t)n * D + l] = o + obuf[l];
}

extern "C" void kernel_launch(void* const* d_in, const int* in_sizes, int n_in,
                              void* d_out, int out_size, void* d_ws, size_t ws_size,
                              hipStream_t stream) {
    const float* x   = (const float*)d_in[0];
    const int*   nbr = (const int*)d_in[1];
    float*       out = (float*)d_out;
    const int n_nodes = in_sizes[0] / D;   // 20000
    rgc_kernel<<<n_nodes, 128, 0, stream>>>(x, nbr, out);
}